// Round 11
// baseline (354.054 us; speedup 1.0000x reference)
//
#include <hip/hip_runtime.h>
#include <hip/hip_bf16.h>
#include <cfloat>

#define NN 50000
#define EE 800000
#define CAP 64   // padded slots per dst; P(Poisson(16) > 64) ~ 1e-21 -> never hit

typedef short bf16x8 __attribute__((ext_vector_type(8)));
typedef float f32x4 __attribute__((ext_vector_type(4)));

__device__ __forceinline__ float leaky(float x) { return x > 0.f ? x : 0.2f * x; }

__device__ __forceinline__ ushort f2b(float x) {
  union { float f; uint u; } v; v.f = x;
  uint r = (v.u + 0x7fffu + ((v.u >> 16) & 1u)) >> 16;
  return (ushort)r;
}

// ---- fused prep: cast h/Wg1/Wg2/Wfc to bf16 + zero cursor, one dispatch ----
#define NH4   (NN * 256 / 4)
#define NW14  (256 * 256 / 4)
#define NW24  (256 * 256 / 4)
#define NWF4  (256 * 512 / 4)
#define NC4   (2 * NN / 4)
#define B0 NH4
#define B1 (B0 + NW14)
#define B2 (B1 + NW24)
#define B3 (B2 + NWF4)
#define B4 (B3 + NC4)

__global__ __launch_bounds__(256) void fused_prep(const float* __restrict__ h,
                                                  const float* __restrict__ Wg1,
                                                  const float* __restrict__ Wg2,
                                                  const float* __restrict__ Wfc,
                                                  ushort* __restrict__ hb,
                                                  ushort* __restrict__ wg1b,
                                                  ushort* __restrict__ wg2b,
                                                  ushort* __restrict__ wfcb,
                                                  int* __restrict__ cursor) {
  int idx = blockIdx.x * blockDim.x + threadIdx.x;
  const float* in;
  ushort* outp;
  int off;
  if (idx < B0) { in = h; outp = hb; off = idx; }
  else if (idx < B1) { in = Wg1; outp = wg1b; off = idx - B0; }
  else if (idx < B2) { in = Wg2; outp = wg2b; off = idx - B1; }
  else if (idx < B3) { in = Wfc; outp = wfcb; off = idx - B2; }
  else if (idx < B4) {
    *(int4*)(cursor + (idx - B3) * 4) = make_int4(0, 0, 0, 0);
    return;
  } else return;
  float4 v = *(const float4*)(in + (size_t)off * 4);
  ushort4 o;
  o.x = f2b(v.x); o.y = f2b(v.y); o.z = f2b(v.z); o.w = f2b(v.w);
  *(ushort4*)(outp + (size_t)off * 4) = o;
}

// ===================================================================
// Merged dispatch: edge scatter + MFMA proj, roles {s,p} 1:1 interleave
// (EPT=4 -> 1563 scatter blocks: 2x resident scatter waves vs {s,p,p}
// EPT=8, raising atomic MLP). Proj epilogue: el/er + per-(row,head)
// int8 quantization (scale packed with el in els.y). feat8 is biased
// uint8 (q+128) -> gat dequant is cvt_f32_ubyte + fma.
// ===================================================================
#define NPROJX ((NN + 127) / 128)        // 391 row-blocks
#define PROJ_BLOCKS (NPROJX * 2 * 2)     // 1564
#define EPT 4
#define NSGRP (2 * EE / EPT)             // 400000 scatter thread-groups
#define MERGED_GRID (PROJ_BLOCKS * 2)    // {s,p} pairs: 1564 each

__global__ __launch_bounds__(256) void proj_scatter(const ushort* __restrict__ A,
                                                    const ushort* __restrict__ B1w,
                                                    const ushort* __restrict__ B2w,
                                                    unsigned char* __restrict__ F8, int M,
                                                    const int* __restrict__ src1,
                                                    const int* __restrict__ dst1,
                                                    const int* __restrict__ src2,
                                                    const int* __restrict__ dst2,
                                                    int* __restrict__ cursor,
                                                    ushort* __restrict__ esrc,
                                                    const float* __restrict__ al1,
                                                    const float* __restrict__ ar1,
                                                    const float* __restrict__ al2,
                                                    const float* __restrict__ ar2,
                                                    float2* __restrict__ els,
                                                    float* __restrict__ er) {
  int r2 = blockIdx.x & 1;
  int g2 = blockIdx.x >> 1;
  if (r2 == 0) {
    // ---------------- scatter: 4 edges/thread ----------------
    int g = g2 * 256 + threadIdx.x;
    const int EG = EE / EPT;                   // 200000 groups per relation
    if (g >= NSGRP) return;
    const int* src;
    const int* dst;
    int off, nodeoff;
    if (g < EG) { src = src1; dst = dst1; off = g * EPT; nodeoff = 0; }
    else { src = src2; dst = dst2; off = (g - EG) * EPT; nodeoff = NN; }
    int4 da = *(const int4*)(dst + off);
    int4 sa = *(const int4*)(src + off);
    int n0 = nodeoff + da.x, n1 = nodeoff + da.y, n2 = nodeoff + da.z, n3 = nodeoff + da.w;
    int p0 = atomicAdd(&cursor[n0], 1);
    int p1 = atomicAdd(&cursor[n1], 1);
    int p2 = atomicAdd(&cursor[n2], 1);
    int p3 = atomicAdd(&cursor[n3], 1);
    if (p0 < CAP) esrc[(size_t)n0 * CAP + p0] = (ushort)sa.x;
    if (p1 < CAP) esrc[(size_t)n1 * CAP + p1] = (ushort)sa.y;
    if (p2 < CAP) esrc[(size_t)n2 * CAP + p2] = (ushort)sa.z;
    if (p3 < CAP) esrc[(size_t)n3 * CAP + p3] = (ushort)sa.w;
    return;
  }
  // ---------------- MFMA proj: feat[z][M,256] = h @ Wz^T ----------------
  __shared__ __align__(16) ushort As[128][40];
  __shared__ __align__(16) ushort Bs[128][40];
  int pb = g2;
  if (pb >= PROJ_BLOCKS) return;
  int bz = pb / (NPROJX * 2);
  int rem = pb - bz * (NPROJX * 2);
  int by = rem / NPROJX;
  int bx = rem - by * NPROJX;
  const ushort* B = bz ? B2w : B1w;
  unsigned char* F8z = F8 + (size_t)bz * NN * 256;
  int t = threadIdx.x;
  int wave = t >> 6, lane = t & 63;
  int m0 = bx * 128, n0 = by * 128;
  int wm = (wave >> 1) * 64, wn = (wave & 1) * 64;
  int quad = lane >> 4, l15 = lane & 15;
  f32x4 acc[4][4] = {};
  for (int k0 = 0; k0 < 256; k0 += 32) {
#pragma unroll
    for (int i = 0; i < 2; ++i) {
      int c = t + 256 * i;
      int row = c >> 2, ko = (c & 3) * 8;
      uint4 av = make_uint4(0u, 0u, 0u, 0u);
      int gr = m0 + row;
      if (gr < M) av = *(const uint4*)(A + (size_t)gr * 256 + k0 + ko);
      *(uint4*)&As[row][ko] = av;
      uint4 bv = *(const uint4*)(B + (size_t)(n0 + row) * 256 + k0 + ko);
      *(uint4*)&Bs[row][ko] = bv;
    }
    __syncthreads();
    bf16x8 af[4], bf[4];
#pragma unroll
    for (int mt = 0; mt < 4; ++mt) af[mt] = *(const bf16x8*)&As[wm + mt * 16 + l15][quad * 8];
#pragma unroll
    for (int nt = 0; nt < 4; ++nt) bf[nt] = *(const bf16x8*)&Bs[wn + nt * 16 + l15][quad * 8];
#pragma unroll
    for (int mt = 0; mt < 4; ++mt)
#pragma unroll
      for (int nt = 0; nt < 4; ++nt)
        acc[mt][nt] = __builtin_amdgcn_mfma_f32_16x16x32_bf16(af[mt], bf[nt], acc[mt][nt], 0, 0, 0);
    __syncthreads();
  }
  // ---- epilogue: el/er + per-(row,head) int8 quantization ----
  const float* alz = bz ? al2 : al1;
  const float* arz = bz ? ar2 : ar1;
  int hA = (n0 + wn) >> 6;   // head fully owned by this wave
  float a_al[4], a_ar[4];
#pragma unroll
  for (int nt = 0; nt < 4; ++nt) {
    int c = n0 + wn + nt * 16 + l15;
    a_al[nt] = alz[c];
    a_ar[nt] = arz[c];
  }
#pragma unroll
  for (int mt = 0; mt < 4; ++mt)
#pragma unroll
    for (int r = 0; r < 4; ++r) {
      float pl = acc[mt][0][r] * a_al[0] + acc[mt][1][r] * a_al[1]
               + acc[mt][2][r] * a_al[2] + acc[mt][3][r] * a_al[3];
      float pr = acc[mt][0][r] * a_ar[0] + acc[mt][1][r] * a_ar[1]
               + acc[mt][2][r] * a_ar[2] + acc[mt][3][r] * a_ar[3];
      float am = fmaxf(fmaxf(fabsf(acc[mt][0][r]), fabsf(acc[mt][1][r])),
                       fmaxf(fabsf(acc[mt][2][r]), fabsf(acc[mt][3][r])));
#pragma unroll
      for (int o = 1; o < 16; o <<= 1) {
        pl += __shfl_xor(pl, o);
        pr += __shfl_xor(pr, o);
        am = fmaxf(am, __shfl_xor(am, o));
      }
      int row = m0 + wm + mt * 16 + quad * 4 + r;
      if (row < M) {
        float qinv = (am > 0.f) ? 127.f / am : 0.f;
        if (l15 == 0) {
          int gn = bz * NN + row;
          els[gn * 4 + hA] = make_float2(pl, am * (1.f / 127.f));
          er[gn * 4 + hA] = pr;
        }
#pragma unroll
        for (int nt = 0; nt < 4; ++nt) {
          int qu = (int)rintf(acc[mt][nt][r] * qinv) + 128;
          F8z[(size_t)row * 256 + n0 + wn + nt * 16 + l15] = (unsigned char)qu;
        }
      }
    }
}

// ------- MFMA FC: out[M,256] fp32 = o1@Wfc[:,:256]^T + o2@Wfc[:,256:]^T + bias -------
__global__ __launch_bounds__(256) void mfma_fc(const ushort* __restrict__ A0,
                                               const ushort* __restrict__ A1,
                                               const ushort* __restrict__ B,  // [256,512] bf16
                                               const float* __restrict__ bias,
                                               float* __restrict__ C, int M) {
  __shared__ __align__(16) ushort As[128][40];
  __shared__ __align__(16) ushort Bs[128][40];
  int t = threadIdx.x;
  int wave = t >> 6, lane = t & 63;
  int m0 = blockIdx.x * 128, n0 = blockIdx.y * 128;
  int wm = (wave >> 1) * 64, wn = (wave & 1) * 64;
  int quad = lane >> 4, l15 = lane & 15;
  f32x4 acc[4][4] = {};
  for (int k0 = 0; k0 < 512; k0 += 32) {
    const ushort* Asrc = (k0 < 256) ? A0 : A1;
    int ka = k0 & 255;
#pragma unroll
    for (int i = 0; i < 2; ++i) {
      int c = t + 256 * i;
      int row = c >> 2, ko = (c & 3) * 8;
      uint4 av = make_uint4(0u, 0u, 0u, 0u);
      int gr = m0 + row;
      if (gr < M) av = *(const uint4*)(Asrc + (size_t)gr * 256 + ka + ko);
      *(uint4*)&As[row][ko] = av;
      uint4 bv = *(const uint4*)(B + (size_t)(n0 + row) * 512 + k0 + ko);
      *(uint4*)&Bs[row][ko] = bv;
    }
    __syncthreads();
    bf16x8 af[4], bf[4];
#pragma unroll
    for (int mt = 0; mt < 4; ++mt) af[mt] = *(const bf16x8*)&As[wm + mt * 16 + l15][quad * 8];
#pragma unroll
    for (int nt = 0; nt < 4; ++nt) bf[nt] = *(const bf16x8*)&Bs[wn + nt * 16 + l15][quad * 8];
#pragma unroll
    for (int mt = 0; mt < 4; ++mt)
#pragma unroll
      for (int nt = 0; nt < 4; ++nt)
        acc[mt][nt] = __builtin_amdgcn_mfma_f32_16x16x32_bf16(af[mt], bf[nt], acc[mt][nt], 0, 0, 0);
    __syncthreads();
  }
#pragma unroll
  for (int mt = 0; mt < 4; ++mt)
#pragma unroll
    for (int r = 0; r < 4; ++r) {
      int row = m0 + wm + mt * 16 + quad * 4 + r;
      if (row < M) {
#pragma unroll
        for (int nt = 0; nt < 4; ++nt) {
          int col = n0 + wn + nt * 16 + l15;
          C[(size_t)row * 256 + col] = acc[mt][nt][r] + bias[col];
        }
      }
    }
}

// ---- fused softmax + accumulate over int8 feat: blocked halves, 8 edges
// in flight per wave; dequant = cvt_f32_ubyte + fma, deferred -128 fix ----
__global__ __launch_bounds__(256) void gat_accum(const unsigned char* __restrict__ f8,
                                                 const float2* __restrict__ els,
                                                 const float* __restrict__ er,
                                                 const ushort* __restrict__ esrc,
                                                 const int* __restrict__ deg,
                                                 const float* __restrict__ b1,
                                                 const float* __restrict__ b2,
                                                 ushort* __restrict__ o1,
                                                 ushort* __restrict__ o2) {
  int n = blockIdx.x * 4 + (threadIdx.x >> 6);
  if (n >= 2 * NN) return;
  int lane = threadIdx.x & 63;
  int half = lane >> 5;      // which 4-edge sub-block this half-wave handles
  int l32 = lane & 31;       // covers cols [l32*8, l32*8+8)
  int h = l32 >> 3;          // head of those 8 cols
  int d = min(deg[n], CAP);
  int nodeoff = (n < NN) ? 0 : NN;
  const ushort* lst = esrc + (size_t)n * CAP;  // 128B-aligned
  float erh = er[n * 4 + h];
  float dsum0 = 0.f, dsum1 = 0.f, xsum = 0.f;
  float acc[8] = {0.f, 0.f, 0.f, 0.f, 0.f, 0.f, 0.f, 0.f};
  int i = 0;
  for (; i + 8 <= d; i += 8) {
    ushort4 idx = *(const ushort4*)(lst + i + half * 4);  // this half's 4 indices
    int s0 = idx.x + nodeoff, s1 = idx.y + nodeoff;
    int s2 = idx.z + nodeoff, s3 = idx.w + nodeoff;
    uint2 f0 = *(const uint2*)(f8 + (size_t)s0 * 256 + l32 * 8);
    uint2 f1 = *(const uint2*)(f8 + (size_t)s1 * 256 + l32 * 8);
    uint2 f2 = *(const uint2*)(f8 + (size_t)s2 * 256 + l32 * 8);
    uint2 f3 = *(const uint2*)(f8 + (size_t)s3 * 256 + l32 * 8);
    float2 e0 = els[s0 * 4 + h];
    float2 e1 = els[s1 * 4 + h];
    float2 e2 = els[s2 * 4 + h];
    float2 e3 = els[s3 * 4 + h];
    float x0 = __expf(leaky(e0.x + erh));
    float x1 = __expf(leaky(e1.x + erh));
    float x2 = __expf(leaky(e2.x + erh));
    float x3 = __expf(leaky(e3.x + erh));
    float w0 = x0 * e0.y, w1 = x1 * e1.y, w2 = x2 * e2.y, w3 = x3 * e3.y;
    dsum0 += x0 + x1;
    dsum1 += x2 + x3;
    xsum += (w0 + w1) + (w2 + w3);
    acc[0] += w0 * (float)( f0.x        & 0xffu);
    acc[1] += w0 * (float)((f0.x >> 8 ) & 0xffu);
    acc[2] += w0 * (float)((f0.x >> 16) & 0xffu);
    acc[3] += w0 * (float)( f0.x >> 24);
    acc[4] += w0 * (float)( f0.y        & 0xffu);
    acc[5] += w0 * (float)((f0.y >> 8 ) & 0xffu);
    acc[6] += w0 * (float)((f0.y >> 16) & 0xffu);
    acc[7] += w0 * (float)( f0.y >> 24);
    acc[0] += w1 * (float)( f1.x        & 0xffu);
    acc[1] += w1 * (float)((f1.x >> 8 ) & 0xffu);
    acc[2] += w1 * (float)((f1.x >> 16) & 0xffu);
    acc[3] += w1 * (float)( f1.x >> 24);
    acc[4] += w1 * (float)( f1.y        & 0xffu);
    acc[5] += w1 * (float)((f1.y >> 8 ) & 0xffu);
    acc[6] += w1 * (float)((f1.y >> 16) & 0xffu);
    acc[7] += w1 * (float)( f1.y >> 24);
    acc[0] += w2 * (float)( f2.x        & 0xffu);
    acc[1] += w2 * (float)((f2.x >> 8 ) & 0xffu);
    acc[2] += w2 * (float)((f2.x >> 16) & 0xffu);
    acc[3] += w2 * (float)( f2.x >> 24);
    acc[4] += w2 * (float)( f2.y        & 0xffu);
    acc[5] += w2 * (float)((f2.y >> 8 ) & 0xffu);
    acc[6] += w2 * (float)((f2.y >> 16) & 0xffu);
    acc[7] += w2 * (float)( f2.y >> 24);
    acc[0] += w3 * (float)( f3.x        & 0xffu);
    acc[1] += w3 * (float)((f3.x >> 8 ) & 0xffu);
    acc[2] += w3 * (float)((f3.x >> 16) & 0xffu);
    acc[3] += w3 * (float)( f3.x >> 24);
    acc[4] += w3 * (float)( f3.y        & 0xffu);
    acc[5] += w3 * (float)((f3.y >> 8 ) & 0xffu);
    acc[6] += w3 * (float)((f3.y >> 16) & 0xffu);
    acc[7] += w3 * (float)( f3.y >> 24);
  }
  // tail (< 8 edges): alternate halves per edge
  for (int j = i + half; j < d; j += 2) {
    int sA = lst[j] + nodeoff;
    uint2 fA = *(const uint2*)(f8 + (size_t)sA * 256 + l32 * 8);
    float2 eA = els[sA * 4 + h];
    float xA = __expf(leaky(eA.x + erh));
    float wA = xA * eA.y;
    dsum0 += xA;
    xsum += wA;
    acc[0] += wA * (float)( fA.x        & 0xffu);
    acc[1] += wA * (float)((fA.x >> 8 ) & 0xffu);
    acc[2] += wA * (float)((fA.x >> 16) & 0xffu);
    acc[3] += wA * (float)( fA.x >> 24);
    acc[4] += wA * (float)( fA.y        & 0xffu);
    acc[5] += wA * (float)((fA.y >> 8 ) & 0xffu);
    acc[6] += wA * (float)((fA.y >> 16) & 0xffu);
    acc[7] += wA * (float)( fA.y >> 24);
  }
  // deferred bias correction (feat8 stores q+128): acc -= 128 * sum(w)
#pragma unroll
  for (int j = 0; j < 8; ++j) acc[j] -= 128.f * xsum;
  float dsum = dsum0 + dsum1;
  // combine the two halves (lane ^ 32 holds the other sub-block's partials)
  dsum += __shfl_xor(dsum, 32);
#pragma unroll
  for (int j = 0; j < 8; ++j) acc[j] += __shfl_xor(acc[j], 32);
  if (half == 0) {
    float inv = (d > 0) ? 1.f / dsum : 0.f;
    const float* bias = (n < NN) ? b1 : b2;
    ushort* outp = (n < NN) ? (o1 + (size_t)n * 256) : (o2 + (size_t)(n - NN) * 256);
    float4 bv0 = *(const float4*)(bias + l32 * 8);
    float4 bv1 = *(const float4*)(bias + l32 * 8 + 4);
    uint4 ov;
    ov.x = (uint)f2b(acc[0] * inv + bv0.x) | ((uint)f2b(acc[1] * inv + bv0.y) << 16);
    ov.y = (uint)f2b(acc[2] * inv + bv0.z) | ((uint)f2b(acc[3] * inv + bv0.w) << 16);
    ov.z = (uint)f2b(acc[4] * inv + bv1.x) | ((uint)f2b(acc[5] * inv + bv1.y) << 16);
    ov.w = (uint)f2b(acc[6] * inv + bv1.z) | ((uint)f2b(acc[7] * inv + bv1.w) << 16);
    *(uint4*)(outp + l32 * 8) = ov;
  }
}

extern "C" void kernel_launch(void* const* d_in, const int* in_sizes, int n_in,
                              void* d_out, int out_size, void* d_ws, size_t ws_size,
                              hipStream_t stream) {
  const float* h   = (const float*)d_in[0];
  const float* Wg1 = (const float*)d_in[1];
  const float* al1 = (const float*)d_in[2];
  const float* ar1 = (const float*)d_in[3];
  const float* b1  = (const float*)d_in[4];
  const float* Wg2 = (const float*)d_in[5];
  const float* al2 = (const float*)d_in[6];
  const float* ar2 = (const float*)d_in[7];
  const float* b2  = (const float*)d_in[8];
  const float* Wfc = (const float*)d_in[9];
  const float* bfc = (const float*)d_in[10];
  const int* src1  = (const int*)d_in[11];
  const int* dst1  = (const int*)d_in[12];
  const int* src2  = (const int*)d_in[13];
  const int* dst2  = (const int*)d_in[14];
  float* out = (float*)d_out;

  const int N = NN;
  const int N2 = 2 * N;
  char* ws = (char*)d_ws;
  size_t pos = 0;
  auto alloc = [&](size_t bytes) -> void* {
    void* p = ws + pos;
    pos += (bytes + 255) & ~(size_t)255;
    return p;
  };
  unsigned char* f8 = (unsigned char*)alloc((size_t)N2 * 256);  // int8 feat (biased)
  ushort* hb    = (ushort*)alloc((size_t)N * 256 * 2);   // bf16 h ; o1b aliases after proj
  ushort* o2b   = (ushort*)alloc((size_t)N * 256 * 2);
  ushort* wg1b  = (ushort*)alloc((size_t)256 * 256 * 2);
  ushort* wg2b  = (ushort*)alloc((size_t)256 * 256 * 2);
  ushort* wfcb  = (ushort*)alloc((size_t)256 * 512 * 2);
  float2* els   = (float2*)alloc((size_t)N2 * 4 * 8);    // (el, dequant scale)
  float* er     = (float*)alloc((size_t)N2 * 4 * 4);
  int* cursor   = (int*)alloc((size_t)N2 * 4);           // becomes degree after scatter
  ushort* esrc  = (ushort*)alloc((size_t)N2 * CAP * 2);  // padded slots (u16, L2-resident)
  ushort* o1b = hb;  // alias: hb dead after proj

  // Prep: all casts + zero cursor (one dispatch)
  fused_prep<<<(B4 + 255) / 256, 256, 0, stream>>>(h, Wg1, Wg2, Wfc, hb, wg1b, wg2b, wfcb, cursor);

  // Merged scatter || proj (+el/er + int8-quant epilogue), {s,p} 1:1 interleave.
  proj_scatter<<<MERGED_GRID, 256, 0, stream>>>(
      hb, wg1b, wg2b, f8, N, src1, dst1, src2, dst2, cursor, esrc,
      al1, ar1, al2, ar2, els, er);

  // Fused softmax + accumulate over int8 feat
  gat_accum<<<(N2 + 3) / 4, 256, 0, stream>>>(f8, els, er, esrc, cursor, b1, b2, o1b, o2b);

  // Semantic fusion FC
  mfma_fc<<<dim3((N + 127) / 128, 2), 256, 0, stream>>>(o1b, o2b, wfcb, bfc, out, N);
}

// Round 12
// 348.527 us; speedup vs baseline: 1.0159x; 1.0159x over previous
//
#include <hip/hip_runtime.h>
#include <hip/hip_bf16.h>
#include <cfloat>

#define NN 50000
#define EE 800000
#define CAP 64   // padded slots per dst; P(Poisson(16) > 64) ~ 1e-21 -> never hit

typedef short bf16x8 __attribute__((ext_vector_type(8)));
typedef float f32x4 __attribute__((ext_vector_type(4)));

__device__ __forceinline__ float leaky(float x) { return x > 0.f ? x : 0.2f * x; }

__device__ __forceinline__ ushort f2b(float x) {
  union { float f; uint u; } v; v.f = x;
  uint r = (v.u + 0x7fffu + ((v.u >> 16) & 1u)) >> 16;
  return (ushort)r;
}

// ---- fused prep: cast h/Wg1/Wg2/Wfc to bf16 + zero cursor, one dispatch ----
#define NH4   (NN * 256 / 4)
#define NW14  (256 * 256 / 4)
#define NW24  (256 * 256 / 4)
#define NWF4  (256 * 512 / 4)
#define NC4   (2 * NN / 4)
#define B0 NH4
#define B1 (B0 + NW14)
#define B2 (B1 + NW24)
#define B3 (B2 + NWF4)
#define B4 (B3 + NC4)

__global__ __launch_bounds__(256) void fused_prep(const float* __restrict__ h,
                                                  const float* __restrict__ Wg1,
                                                  const float* __restrict__ Wg2,
                                                  const float* __restrict__ Wfc,
                                                  ushort* __restrict__ hb,
                                                  ushort* __restrict__ wg1b,
                                                  ushort* __restrict__ wg2b,
                                                  ushort* __restrict__ wfcb,
                                                  int* __restrict__ cursor) {
  int idx = blockIdx.x * blockDim.x + threadIdx.x;
  const float* in;
  ushort* outp;
  int off;
  if (idx < B0) { in = h; outp = hb; off = idx; }
  else if (idx < B1) { in = Wg1; outp = wg1b; off = idx - B0; }
  else if (idx < B2) { in = Wg2; outp = wg2b; off = idx - B1; }
  else if (idx < B3) { in = Wfc; outp = wfcb; off = idx - B2; }
  else if (idx < B4) {
    *(int4*)(cursor + (idx - B3) * 4) = make_int4(0, 0, 0, 0);
    return;
  } else return;
  float4 v = *(const float4*)(in + (size_t)off * 4);
  ushort4 o;
  o.x = f2b(v.x); o.y = f2b(v.y); o.z = f2b(v.z); o.w = f2b(v.w);
  *(ushort4*)(outp + (size_t)off * 4) = o;
}

// ===================================================================
// Merged dispatch: edge scatter + MFMA proj, roles {s,p,p} interleaved
// (EPT=8, 782 scatter : 1564 proj — measured-best atomic operating
// point; more scatter concurrency REGRESSES, r11). Proj epilogue:
// el/er (wave's 64 cols == one head) + per-(row,head) int8 quant
// (scale packed with el in els.y). feat8 is biased uint8 (q+128).
// ===================================================================
#define NPROJX ((NN + 127) / 128)        // 391 row-blocks
#define PROJ_BLOCKS (NPROJX * 2 * 2)     // 1564
#define SCAT_BLOCKS (2 * EE / 8 / 256 + 1) // 782 (8 edges/thread)
#define MERGED_GRID (SCAT_BLOCKS * 3)    // {s,p,p} triples

__global__ __launch_bounds__(256) void proj_scatter(const ushort* __restrict__ A,
                                                    const ushort* __restrict__ B1w,
                                                    const ushort* __restrict__ B2w,
                                                    unsigned char* __restrict__ F8, int M,
                                                    const int* __restrict__ src1,
                                                    const int* __restrict__ dst1,
                                                    const int* __restrict__ src2,
                                                    const int* __restrict__ dst2,
                                                    int* __restrict__ cursor,
                                                    ushort* __restrict__ esrc,
                                                    const float* __restrict__ al1,
                                                    const float* __restrict__ ar1,
                                                    const float* __restrict__ al2,
                                                    const float* __restrict__ ar2,
                                                    float2* __restrict__ els,
                                                    float* __restrict__ er) {
  int r3 = blockIdx.x % 3;
  int g3 = blockIdx.x / 3;
  if (r3 == 0) {
    // ---------------- scatter: 8 edges/thread ----------------
    int g = g3 * 256 + threadIdx.x;
    const int EG = EE / 8;
    if (g >= 2 * EG) return;
    const int* src;
    const int* dst;
    int off, nodeoff;
    if (g < EG) { src = src1; dst = dst1; off = g * 8; nodeoff = 0; }
    else { src = src2; dst = dst2; off = (g - EG) * 8; nodeoff = NN; }
    int4 da = *(const int4*)(dst + off);
    int4 db = *(const int4*)(dst + off + 4);
    int4 sa = *(const int4*)(src + off);
    int4 sb = *(const int4*)(src + off + 4);
    int n0 = nodeoff + da.x, n1 = nodeoff + da.y, n2 = nodeoff + da.z, n3 = nodeoff + da.w;
    int n4 = nodeoff + db.x, n5 = nodeoff + db.y, n6 = nodeoff + db.z, n7 = nodeoff + db.w;
    int p0 = atomicAdd(&cursor[n0], 1);
    int p1 = atomicAdd(&cursor[n1], 1);
    int p2 = atomicAdd(&cursor[n2], 1);
    int p3 = atomicAdd(&cursor[n3], 1);
    int p4 = atomicAdd(&cursor[n4], 1);
    int p5 = atomicAdd(&cursor[n5], 1);
    int p6 = atomicAdd(&cursor[n6], 1);
    int p7 = atomicAdd(&cursor[n7], 1);
    if (p0 < CAP) esrc[(size_t)n0 * CAP + p0] = (ushort)sa.x;
    if (p1 < CAP) esrc[(size_t)n1 * CAP + p1] = (ushort)sa.y;
    if (p2 < CAP) esrc[(size_t)n2 * CAP + p2] = (ushort)sa.z;
    if (p3 < CAP) esrc[(size_t)n3 * CAP + p3] = (ushort)sa.w;
    if (p4 < CAP) esrc[(size_t)n4 * CAP + p4] = (ushort)sb.x;
    if (p5 < CAP) esrc[(size_t)n5 * CAP + p5] = (ushort)sb.y;
    if (p6 < CAP) esrc[(size_t)n6 * CAP + p6] = (ushort)sb.z;
    if (p7 < CAP) esrc[(size_t)n7 * CAP + p7] = (ushort)sb.w;
    return;
  }
  // ---------------- MFMA proj: feat[z][M,256] = h @ Wz^T ----------------
  __shared__ __align__(16) ushort As[128][40];
  __shared__ __align__(16) ushort Bs[128][40];
  int pb = 2 * g3 + (r3 - 1);
  if (pb >= PROJ_BLOCKS) return;
  int bz = pb / (NPROJX * 2);
  int rem = pb - bz * (NPROJX * 2);
  int by = rem / NPROJX;
  int bx = rem - by * NPROJX;
  const ushort* B = bz ? B2w : B1w;
  unsigned char* F8z = F8 + (size_t)bz * NN * 256;
  int t = threadIdx.x;
  int wave = t >> 6, lane = t & 63;
  int m0 = bx * 128, n0 = by * 128;
  int wm = (wave >> 1) * 64, wn = (wave & 1) * 64;
  int quad = lane >> 4, l15 = lane & 15;
  f32x4 acc[4][4] = {};
  for (int k0 = 0; k0 < 256; k0 += 32) {
#pragma unroll
    for (int i = 0; i < 2; ++i) {
      int c = t + 256 * i;
      int row = c >> 2, ko = (c & 3) * 8;
      uint4 av = make_uint4(0u, 0u, 0u, 0u);
      int gr = m0 + row;
      if (gr < M) av = *(const uint4*)(A + (size_t)gr * 256 + k0 + ko);
      *(uint4*)&As[row][ko] = av;
      uint4 bv = *(const uint4*)(B + (size_t)(n0 + row) * 256 + k0 + ko);
      *(uint4*)&Bs[row][ko] = bv;
    }
    __syncthreads();
    bf16x8 af[4], bf[4];
#pragma unroll
    for (int mt = 0; mt < 4; ++mt) af[mt] = *(const bf16x8*)&As[wm + mt * 16 + l15][quad * 8];
#pragma unroll
    for (int nt = 0; nt < 4; ++nt) bf[nt] = *(const bf16x8*)&Bs[wn + nt * 16 + l15][quad * 8];
#pragma unroll
    for (int mt = 0; mt < 4; ++mt)
#pragma unroll
      for (int nt = 0; nt < 4; ++nt)
        acc[mt][nt] = __builtin_amdgcn_mfma_f32_16x16x32_bf16(af[mt], bf[nt], acc[mt][nt], 0, 0, 0);
    __syncthreads();
  }
  // ---- epilogue: el/er + per-(row,head) int8 quantization ----
  const float* alz = bz ? al2 : al1;
  const float* arz = bz ? ar2 : ar1;
  int hA = (n0 + wn) >> 6;   // head fully owned by this wave
  float a_al[4], a_ar[4];
#pragma unroll
  for (int nt = 0; nt < 4; ++nt) {
    int c = n0 + wn + nt * 16 + l15;
    a_al[nt] = alz[c];
    a_ar[nt] = arz[c];
  }
#pragma unroll
  for (int mt = 0; mt < 4; ++mt)
#pragma unroll
    for (int r = 0; r < 4; ++r) {
      float pl = acc[mt][0][r] * a_al[0] + acc[mt][1][r] * a_al[1]
               + acc[mt][2][r] * a_al[2] + acc[mt][3][r] * a_al[3];
      float pr = acc[mt][0][r] * a_ar[0] + acc[mt][1][r] * a_ar[1]
               + acc[mt][2][r] * a_ar[2] + acc[mt][3][r] * a_ar[3];
      float am = fmaxf(fmaxf(fabsf(acc[mt][0][r]), fabsf(acc[mt][1][r])),
                       fmaxf(fabsf(acc[mt][2][r]), fabsf(acc[mt][3][r])));
#pragma unroll
      for (int o = 1; o < 16; o <<= 1) {
        pl += __shfl_xor(pl, o);
        pr += __shfl_xor(pr, o);
        am = fmaxf(am, __shfl_xor(am, o));
      }
      int row = m0 + wm + mt * 16 + quad * 4 + r;
      if (row < M) {
        float qinv = (am > 0.f) ? 127.f / am : 0.f;
        if (l15 == 0) {
          int gn = bz * NN + row;
          els[gn * 4 + hA] = make_float2(pl, am * (1.f / 127.f));
          er[gn * 4 + hA] = pr;
        }
#pragma unroll
        for (int nt = 0; nt < 4; ++nt) {
          int qu = (int)rintf(acc[mt][nt][r] * qinv) + 128;
          F8z[(size_t)row * 256 + n0 + wn + nt * 16 + l15] = (unsigned char)qu;
        }
      }
    }
}

// ------- MFMA FC: out[M,256] fp32 = o1@Wfc[:,:256]^T + o2@Wfc[:,256:]^T + bias -------
__global__ __launch_bounds__(256) void mfma_fc(const ushort* __restrict__ A0,
                                               const ushort* __restrict__ A1,
                                               const ushort* __restrict__ B,  // [256,512] bf16
                                               const float* __restrict__ bias,
                                               float* __restrict__ C, int M) {
  __shared__ __align__(16) ushort As[128][40];
  __shared__ __align__(16) ushort Bs[128][40];
  int t = threadIdx.x;
  int wave = t >> 6, lane = t & 63;
  int m0 = blockIdx.x * 128, n0 = blockIdx.y * 128;
  int wm = (wave >> 1) * 64, wn = (wave & 1) * 64;
  int quad = lane >> 4, l15 = lane & 15;
  f32x4 acc[4][4] = {};
  for (int k0 = 0; k0 < 512; k0 += 32) {
    const ushort* Asrc = (k0 < 256) ? A0 : A1;
    int ka = k0 & 255;
#pragma unroll
    for (int i = 0; i < 2; ++i) {
      int c = t + 256 * i;
      int row = c >> 2, ko = (c & 3) * 8;
      uint4 av = make_uint4(0u, 0u, 0u, 0u);
      int gr = m0 + row;
      if (gr < M) av = *(const uint4*)(Asrc + (size_t)gr * 256 + ka + ko);
      *(uint4*)&As[row][ko] = av;
      uint4 bv = *(const uint4*)(B + (size_t)(n0 + row) * 512 + k0 + ko);
      *(uint4*)&Bs[row][ko] = bv;
    }
    __syncthreads();
    bf16x8 af[4], bf[4];
#pragma unroll
    for (int mt = 0; mt < 4; ++mt) af[mt] = *(const bf16x8*)&As[wm + mt * 16 + l15][quad * 8];
#pragma unroll
    for (int nt = 0; nt < 4; ++nt) bf[nt] = *(const bf16x8*)&Bs[wn + nt * 16 + l15][quad * 8];
#pragma unroll
    for (int mt = 0; mt < 4; ++mt)
#pragma unroll
      for (int nt = 0; nt < 4; ++nt)
        acc[mt][nt] = __builtin_amdgcn_mfma_f32_16x16x32_bf16(af[mt], bf[nt], acc[mt][nt], 0, 0, 0);
    __syncthreads();
  }
#pragma unroll
  for (int mt = 0; mt < 4; ++mt)
#pragma unroll
    for (int r = 0; r < 4; ++r) {
      int row = m0 + wm + mt * 16 + quad * 4 + r;
      if (row < M) {
#pragma unroll
        for (int nt = 0; nt < 4; ++nt) {
          int col = n0 + wn + nt * 16 + l15;
          C[(size_t)row * 256 + col] = acc[mt][nt][r] + bias[col];
        }
      }
    }
}

// ---- fused softmax + accumulate over int8 feat: blocked halves, 8 edges
// in flight per wave; dequant = cvt_f32_ubyte + fma, deferred -128 fix ----
__global__ __launch_bounds__(256) void gat_accum(const unsigned char* __restrict__ f8,
                                                 const float2* __restrict__ els,
                                                 const float* __restrict__ er,
                                                 const ushort* __restrict__ esrc,
                                                 const int* __restrict__ deg,
                                                 const float* __restrict__ b1,
                                                 const float* __restrict__ b2,
                                                 ushort* __restrict__ o1,
                                                 ushort* __restrict__ o2) {
  int n = blockIdx.x * 4 + (threadIdx.x >> 6);
  if (n >= 2 * NN) return;
  int lane = threadIdx.x & 63;
  int half = lane >> 5;      // which 4-edge sub-block this half-wave handles
  int l32 = lane & 31;       // covers cols [l32*8, l32*8+8)
  int h = l32 >> 3;          // head of those 8 cols
  int d = min(deg[n], CAP);
  int nodeoff = (n < NN) ? 0 : NN;
  const ushort* lst = esrc + (size_t)n * CAP;  // 128B-aligned
  float erh = er[n * 4 + h];
  float dsum0 = 0.f, dsum1 = 0.f, xsum = 0.f;
  float acc[8] = {0.f, 0.f, 0.f, 0.f, 0.f, 0.f, 0.f, 0.f};
  int i = 0;
  for (; i + 8 <= d; i += 8) {
    ushort4 idx = *(const ushort4*)(lst + i + half * 4);  // this half's 4 indices
    int s0 = idx.x + nodeoff, s1 = idx.y + nodeoff;
    int s2 = idx.z + nodeoff, s3 = idx.w + nodeoff;
    uint2 f0 = *(const uint2*)(f8 + (size_t)s0 * 256 + l32 * 8);
    uint2 f1 = *(const uint2*)(f8 + (size_t)s1 * 256 + l32 * 8);
    uint2 f2 = *(const uint2*)(f8 + (size_t)s2 * 256 + l32 * 8);
    uint2 f3 = *(const uint2*)(f8 + (size_t)s3 * 256 + l32 * 8);
    float2 e0 = els[s0 * 4 + h];
    float2 e1 = els[s1 * 4 + h];
    float2 e2 = els[s2 * 4 + h];
    float2 e3 = els[s3 * 4 + h];
    float x0 = __expf(leaky(e0.x + erh));
    float x1 = __expf(leaky(e1.x + erh));
    float x2 = __expf(leaky(e2.x + erh));
    float x3 = __expf(leaky(e3.x + erh));
    float w0 = x0 * e0.y, w1 = x1 * e1.y, w2 = x2 * e2.y, w3 = x3 * e3.y;
    dsum0 += x0 + x1;
    dsum1 += x2 + x3;
    xsum += (w0 + w1) + (w2 + w3);
    acc[0] += w0 * (float)( f0.x        & 0xffu);
    acc[1] += w0 * (float)((f0.x >> 8 ) & 0xffu);
    acc[2] += w0 * (float)((f0.x >> 16) & 0xffu);
    acc[3] += w0 * (float)( f0.x >> 24);
    acc[4] += w0 * (float)( f0.y        & 0xffu);
    acc[5] += w0 * (float)((f0.y >> 8 ) & 0xffu);
    acc[6] += w0 * (float)((f0.y >> 16) & 0xffu);
    acc[7] += w0 * (float)( f0.y >> 24);
    acc[0] += w1 * (float)( f1.x        & 0xffu);
    acc[1] += w1 * (float)((f1.x >> 8 ) & 0xffu);
    acc[2] += w1 * (float)((f1.x >> 16) & 0xffu);
    acc[3] += w1 * (float)( f1.x >> 24);
    acc[4] += w1 * (float)( f1.y        & 0xffu);
    acc[5] += w1 * (float)((f1.y >> 8 ) & 0xffu);
    acc[6] += w1 * (float)((f1.y >> 16) & 0xffu);
    acc[7] += w1 * (float)( f1.y >> 24);
    acc[0] += w2 * (float)( f2.x        & 0xffu);
    acc[1] += w2 * (float)((f2.x >> 8 ) & 0xffu);
    acc[2] += w2 * (float)((f2.x >> 16) & 0xffu);
    acc[3] += w2 * (float)( f2.x >> 24);
    acc[4] += w2 * (float)( f2.y        & 0xffu);
    acc[5] += w2 * (float)((f2.y >> 8 ) & 0xffu);
    acc[6] += w2 * (float)((f2.y >> 16) & 0xffu);
    acc[7] += w2 * (float)( f2.y >> 24);
    acc[0] += w3 * (float)( f3.x        & 0xffu);
    acc[1] += w3 * (float)((f3.x >> 8 ) & 0xffu);
    acc[2] += w3 * (float)((f3.x >> 16) & 0xffu);
    acc[3] += w3 * (float)( f3.x >> 24);
    acc[4] += w3 * (float)( f3.y        & 0xffu);
    acc[5] += w3 * (float)((f3.y >> 8 ) & 0xffu);
    acc[6] += w3 * (float)((f3.y >> 16) & 0xffu);
    acc[7] += w3 * (float)( f3.y >> 24);
  }
  // tail (< 8 edges): alternate halves per edge
  for (int j = i + half; j < d; j += 2) {
    int sA = lst[j] + nodeoff;
    uint2 fA = *(const uint2*)(f8 + (size_t)sA * 256 + l32 * 8);
    float2 eA = els[sA * 4 + h];
    float xA = __expf(leaky(eA.x + erh));
    float wA = xA * eA.y;
    dsum0 += xA;
    xsum += wA;
    acc[0] += wA * (float)( fA.x        & 0xffu);
    acc[1] += wA * (float)((fA.x >> 8 ) & 0xffu);
    acc[2] += wA * (float)((fA.x >> 16) & 0xffu);
    acc[3] += wA * (float)( fA.x >> 24);
    acc[4] += wA * (float)( fA.y        & 0xffu);
    acc[5] += wA * (float)((fA.y >> 8 ) & 0xffu);
    acc[6] += wA * (float)((fA.y >> 16) & 0xffu);
    acc[7] += wA * (float)( fA.y >> 24);
  }
  // deferred bias correction (feat8 stores q+128): acc -= 128 * sum(w)
#pragma unroll
  for (int j = 0; j < 8; ++j) acc[j] -= 128.f * xsum;
  float dsum = dsum0 + dsum1;
  // combine the two halves (lane ^ 32 holds the other sub-block's partials)
  dsum += __shfl_xor(dsum, 32);
#pragma unroll
  for (int j = 0; j < 8; ++j) acc[j] += __shfl_xor(acc[j], 32);
  if (half == 0) {
    float inv = (d > 0) ? 1.f / dsum : 0.f;
    const float* bias = (n < NN) ? b1 : b2;
    ushort* outp = (n < NN) ? (o1 + (size_t)n * 256) : (o2 + (size_t)(n - NN) * 256);
    float4 bv0 = *(const float4*)(bias + l32 * 8);
    float4 bv1 = *(const float4*)(bias + l32 * 8 + 4);
    uint4 ov;
    ov.x = (uint)f2b(acc[0] * inv + bv0.x) | ((uint)f2b(acc[1] * inv + bv0.y) << 16);
    ov.y = (uint)f2b(acc[2] * inv + bv0.z) | ((uint)f2b(acc[3] * inv + bv0.w) << 16);
    ov.z = (uint)f2b(acc[4] * inv + bv1.x) | ((uint)f2b(acc[5] * inv + bv1.y) << 16);
    ov.w = (uint)f2b(acc[6] * inv + bv1.z) | ((uint)f2b(acc[7] * inv + bv1.w) << 16);
    *(uint4*)(outp + l32 * 8) = ov;
  }
}

extern "C" void kernel_launch(void* const* d_in, const int* in_sizes, int n_in,
                              void* d_out, int out_size, void* d_ws, size_t ws_size,
                              hipStream_t stream) {
  const float* h   = (const float*)d_in[0];
  const float* Wg1 = (const float*)d_in[1];
  const float* al1 = (const float*)d_in[2];
  const float* ar1 = (const float*)d_in[3];
  const float* b1  = (const float*)d_in[4];
  const float* Wg2 = (const float*)d_in[5];
  const float* al2 = (const float*)d_in[6];
  const float* ar2 = (const float*)d_in[7];
  const float* b2  = (const float*)d_in[8];
  const float* Wfc = (const float*)d_in[9];
  const float* bfc = (const float*)d_in[10];
  const int* src1  = (const int*)d_in[11];
  const int* dst1  = (const int*)d_in[12];
  const int* src2  = (const int*)d_in[13];
  const int* dst2  = (const int*)d_in[14];
  float* out = (float*)d_out;

  const int N = NN;
  const int N2 = 2 * N;
  char* ws = (char*)d_ws;
  size_t pos = 0;
  auto alloc = [&](size_t bytes) -> void* {
    void* p = ws + pos;
    pos += (bytes + 255) & ~(size_t)255;
    return p;
  };
  unsigned char* f8 = (unsigned char*)alloc((size_t)N2 * 256);  // int8 feat (biased)
  ushort* hb    = (ushort*)alloc((size_t)N * 256 * 2);   // bf16 h ; o1b aliases after proj
  ushort* o2b   = (ushort*)alloc((size_t)N * 256 * 2);
  ushort* wg1b  = (ushort*)alloc((size_t)256 * 256 * 2);
  ushort* wg2b  = (ushort*)alloc((size_t)256 * 256 * 2);
  ushort* wfcb  = (ushort*)alloc((size_t)256 * 512 * 2);
  float2* els   = (float2*)alloc((size_t)N2 * 4 * 8);    // (el, dequant scale)
  float* er     = (float*)alloc((size_t)N2 * 4 * 4);
  int* cursor   = (int*)alloc((size_t)N2 * 4);           // becomes degree after scatter
  ushort* esrc  = (ushort*)alloc((size_t)N2 * CAP * 2);  // padded slots (u16, L2-resident)
  ushort* o1b = hb;  // alias: hb dead after proj

  // Prep: all casts + zero cursor (one dispatch)
  fused_prep<<<(B4 + 255) / 256, 256, 0, stream>>>(h, Wg1, Wg2, Wfc, hb, wg1b, wg2b, wfcb, cursor);

  // Merged scatter || proj (+el/er + int8-quant epilogue), {s,p,p} interleaved.
  proj_scatter<<<MERGED_GRID, 256, 0, stream>>>(
      hb, wg1b, wg2b, f8, N, src1, dst1, src2, dst2, cursor, esrc,
      al1, ar1, al2, ar2, els, er);

  // Fused softmax + accumulate over int8 feat
  gat_accum<<<(N2 + 3) / 4, 256, 0, stream>>>(f8, els, er, esrc, cursor, b1, b2, o1b, o2b);

  // Semantic fusion FC
  mfma_fc<<<dim3((N + 127) / 128, 2), 256, 0, stream>>>(o1b, o2b, wfcb, bfc, out, N);
}